// Round 6
// baseline (782.203 us; speedup 1.0000x reference)
//
#include <hip/hip_runtime.h>
#include <hip/hip_bf16.h>
#include <hip/hip_fp16.h>
#include <cstdint>
#include <cstddef>
#include <cstring>

using bf16 = __hip_bfloat16;

constexpr int TS    = 1024;
constexpr int DIM   = 1024;
constexpr int MEMN  = 1024;
constexpr int CMEMN = 256;
constexpr int KVN   = 2304;   // CMEM + MEM + T
constexpr int TMEM  = 1280;   // MEM + CMEM

typedef __attribute__((ext_vector_type(8))) short short8;
typedef __attribute__((ext_vector_type(4))) float f32x4;

__device__ __forceinline__ unsigned short f2bf_us(float f){
    __hip_bfloat16 t = __float2bfloat16(f);
    unsigned short us; memcpy(&us, &t, 2); return us;
}
__device__ __forceinline__ int sw8(int row){ return (row & 7) ^ ((row >> 3) & 7); }

// XOR-swizzled LDS tile (rows of 64 shorts, swizzle on 8-short chunks)
__device__ __forceinline__ short8 ldfrag(const unsigned short* base, int row, int chunk) {
    int ch = chunk ^ sw8(row);
    return *(const short8*)(base + row*64 + ch*8);
}
__device__ __forceinline__ void gl2lds16(const void* g, void* l) {
    __builtin_amdgcn_global_load_lds(
        (const __attribute__((address_space(1))) void*)g,
        (__attribute__((address_space(3))) void*)l, 16, 0, 0);
}

// ---------------- pack: fp32 -> bf16 staging (unchanged, R5-proven) ----------
__global__ __launch_bounds__(256) void pack(
    const float* __restrict__ x, const float* __restrict__ memp,
    const float* __restrict__ cmem, const float* __restrict__ Wq,
    const float* __restrict__ Wkv, const float* __restrict__ Wout,
    const float* __restrict__ cw, const float* __restrict__ pe,
    unsigned short* __restrict__ kvin, unsigned short* __restrict__ wqb,
    unsigned short* __restrict__ wkvb, unsigned short* __restrict__ woutb,
    unsigned short* __restrict__ cw2b, unsigned short* __restrict__ peb)
{
    const size_t t8 = ((size_t)blockIdx.x * 256 + threadIdx.x) * 8;
    unsigned short h[8];
    if (t8 < 9437184) {
        size_t g = t8 >> 10;
        int cc = (int)(t8 & 1023);
        int b = (int)(g / KVN), j = (int)(g % KVN);
        const float* src;
        if (j < CMEMN)      src = cmem + ((size_t)b*CMEMN + j)*1024 + cc;
        else if (j < TMEM)  src = memp + ((size_t)b*MEMN + (j - CMEMN))*1024 + cc;
        else                src = x    + ((size_t)b*TS   + (j - TMEM))*1024 + cc;
        float4 f0 = *(const float4*)src; float4 f1 = *(const float4*)(src + 4);
        h[0]=f2bf_us(f0.x); h[1]=f2bf_us(f0.y); h[2]=f2bf_us(f0.z); h[3]=f2bf_us(f0.w);
        h[4]=f2bf_us(f1.x); h[5]=f2bf_us(f1.y); h[6]=f2bf_us(f1.z); h[7]=f2bf_us(f1.w);
        *(uint4*)(kvin + t8) = *(const uint4*)h;
    } else if (t8 < 13631488) {
        const float* src; unsigned short* dst; float sc = 1.0f;
        if (t8 < 10485760)      { src = Wq   + (t8 - 9437184);  dst = wqb   + (t8 - 9437184); sc = 0.125f; }
        else if (t8 < 12582912) { src = Wkv  + (t8 - 10485760); dst = wkvb  + (t8 - 10485760); }
        else                    { src = Wout + (t8 - 12582912); dst = woutb + (t8 - 12582912); }
        float4 f0 = *(const float4*)src; float4 f1 = *(const float4*)(src + 4);
        h[0]=f2bf_us(f0.x*sc); h[1]=f2bf_us(f0.y*sc); h[2]=f2bf_us(f0.z*sc); h[3]=f2bf_us(f0.w*sc);
        h[4]=f2bf_us(f1.x*sc); h[5]=f2bf_us(f1.y*sc); h[6]=f2bf_us(f1.z*sc); h[7]=f2bf_us(f1.w*sc);
        *(uint4*)dst = *(const uint4*)h;
    } else if (t8 < 17825792) {
        size_t o8 = t8 - 13631488;
        int o = (int)(o8 >> 12); int rem = (int)(o8 & 4095);
        int r = rem >> 10, i = rem & 1023;
        #pragma unroll
        for (int p = 0; p < 8; ++p) h[p] = f2bf_us(cw[(o << 12) + (i + p)*4 + r]);
        *(uint4*)(cw2b + o8) = *(const uint4*)h;
    } else {
        size_t o8 = t8 - 17825792;
        const float* src = pe + o8;
        float4 f0 = *(const float4*)src; float4 f1 = *(const float4*)(src + 4);
        h[0]=f2bf_us(f0.x); h[1]=f2bf_us(f0.y); h[2]=f2bf_us(f0.z); h[3]=f2bf_us(f0.w);
        h[4]=f2bf_us(f1.x); h[5]=f2bf_us(f1.y); h[6]=f2bf_us(f1.z); h[7]=f2bf_us(f1.w);
        *(uint4*)(peb + o8) = *(const uint4*)h;
    }
}

// ---------------- MFMA GEMM (unchanged, R5-proven) ----------------
template<int EPI, int QMODE>
__global__ __launch_bounds__(256) void gemm_mfma(
    const bf16* __restrict__ Abf, const bf16* __restrict__ Bbf,
    const float* __restrict__ bias, void* __restrict__ Cptr,
    void* __restrict__ C2, int M, int N, int K)
{
    __shared__ alignas(16) unsigned short As[128*64];
    __shared__ alignas(16) unsigned short Bs[128*64];
    const int tid = threadIdx.x, lane = tid & 63, w = tid >> 6;
    const int quad = lane >> 4, colq = lane & 15;
    const int wm = w >> 1, wn = w & 1;
    const int m0 = blockIdx.x * 128, n0 = blockIdx.y * 128;
    size_t abase;
    if (QMODE == 0)      abase = (size_t)m0 * K;
    else if (QMODE == 1) abase = ((size_t)((m0 >> 10)*KVN + TMEM + (m0 & 1023))) * 1024;
    else                 abase = ((size_t)((m0 >> 8)*KVN + CMEMN)) * 1024 + (size_t)(m0 & 255) * 4096;
    const unsigned short* Ag = (const unsigned short*)Abf + abase;
    const unsigned short* Bg = (const unsigned short*)Bbf + (size_t)n0 * K;

    const int srow0 = w*32 + (lane >> 3);
    const int sch2  = lane & 7;

    f32x4 acc[4][4];
    #pragma unroll
    for (int i = 0; i < 4; ++i)
        #pragma unroll
        for (int j = 0; j < 4; ++j) acc[i][j] = (f32x4){0.f,0.f,0.f,0.f};

    for (int k0 = 0; k0 < K; k0 += 64) {
        __syncthreads();
        #pragma unroll
        for (int c = 0; c < 4; ++c) {
            int rr = srow0 + c*8;
            int ch = sch2 ^ sw8(rr);
            gl2lds16(Ag + (size_t)rr*K + k0 + ch*8, &As[(w*32 + c*8)*64]);
            gl2lds16(Bg + (size_t)rr*K + k0 + ch*8, &Bs[(w*32 + c*8)*64]);
        }
        __syncthreads();
        short8 af[4][2], bfr[4][2];
        #pragma unroll
        for (int i = 0; i < 4; ++i) {
            af[i][0]  = ldfrag(As, wm*64 + i*16 + colq, quad);
            af[i][1]  = ldfrag(As, wm*64 + i*16 + colq, 4 + quad);
            bfr[i][0] = ldfrag(Bs, wn*64 + i*16 + colq, quad);
            bfr[i][1] = ldfrag(Bs, wn*64 + i*16 + colq, 4 + quad);
        }
        #pragma unroll
        for (int i = 0; i < 4; ++i)
            #pragma unroll
            for (int j = 0; j < 4; ++j) {
                f32x4 t = __builtin_amdgcn_mfma_f32_16x16x32_bf16(af[i][0], bfr[j][0], acc[i][j], 0, 0, 0);
                acc[i][j] = __builtin_amdgcn_mfma_f32_16x16x32_bf16(af[i][1], bfr[j][1], t, 0, 0, 0);
            }
    }
    if (EPI == 2) {
        const int b = m0 / KVN;
        const int jj0 = (m0 - b*KVN) + wm*64;
        if (n0 < 1024) {
            bf16* kn = (bf16*)Cptr;
            #pragma unroll
            for (int j = 0; j < 4; ++j) {
                int col = n0 + wn*64 + j*16 + colq;
                #pragma unroll
                for (int i = 0; i < 4; ++i)
                    #pragma unroll
                    for (int r = 0; r < 4; ++r)
                        kn[(size_t)(b*KVN + jj0 + i*16 + quad*4 + r)*1024 + col] =
                            __float2bfloat16(acc[i][j][r]);
            }
        } else {
            unsigned short* vp = (unsigned short*)C2;
            #pragma unroll
            for (int j = 0; j < 4; ++j) {
                int col = n0 + wn*64 + j*16 + colq;
                int hh = (col >> 6) & 15, d = col & 63;
                #pragma unroll
                for (int i = 0; i < 4; ++i) {
                    int jjb = jj0 + i*16 + quad*4;
                    ushort4 u;
                    u.x = f2bf_us(acc[i][j][0]); u.y = f2bf_us(acc[i][j][1]);
                    u.z = f2bf_us(acc[i][j][2]); u.w = f2bf_us(acc[i][j][3]);
                    *(ushort4*)(vp + ((size_t)((b*16 + hh)*64 + d))*KVN + jjb) = u;
                }
            }
        }
    } else {
        #pragma unroll
        for (int j = 0; j < 4; ++j) {
            int col = n0 + wn*64 + j*16 + colq;
            float bj = bias ? bias[col] : 0.0f;
            #pragma unroll
            for (int i = 0; i < 4; ++i)
                #pragma unroll
                for (int r = 0; r < 4; ++r) {
                    size_t row = (size_t)(m0 + wm*64 + i*16 + quad*4 + r);
                    float v = acc[i][j][r] + bj;
                    if (EPI == 1) ((bf16*)Cptr)[row*N + col] = __float2bfloat16(v);
                    else          ((float*)Cptr)[row*N + col] = v;
                }
        }
    }
}

// ---------------- Flash attention, rel-pos, MFMA ----------------
// R6: PE B-frags straight from global (L2-resident, VMEM pipe idle);
// K/V double-buffered DMA (stage t+1 before computing t, one barrier/iter);
// LDS 48 KB + launch_bounds(256,3) -> 3 blocks/CU, all 512 blocks resident.
__global__ __launch_bounds__(256, 3) void attn(
    const unsigned short* __restrict__ qg,   // prescaled q bf16 [b*1024+i][1024]
    const unsigned short* __restrict__ kq,   // knat [b*KVN+j][1024]
    const unsigned short* __restrict__ vh,   // Vh [((b*16+h)*64+d)][KVN]
    const unsigned short* __restrict__ peb,  // [h][KVN][64] bf16
    bf16* __restrict__ out)                  // ao [b*1024+i][1024]
{
    __shared__ alignas(16) unsigned short Kt[2][64*64];   // 16 KB
    __shared__ alignas(16) unsigned short Vt[2][64*64];   // 16 KB, Vt[d][j]
    __shared__ alignas(16) unsigned short Pb[128*64];     // 16 KB, Q then P

    const int tid  = threadIdx.x;
    const int lane = tid & 63, w = tid >> 6;
    const int quad = lane >> 4, colq = lane & 15;
    const int jr = lane >> 3, l7 = lane & 7;

    const int bx = blockIdx.x;
    const int b = bx & 3, h = (bx >> 2) & 15;
    const int q0 = (7 - (bx >> 6)) * 128;      // heavy q-tiles dispatch first

    const size_t kqbase = (size_t)b * KVN * 1024 + h*64;
    const size_t vhbase = ((size_t)(b*16 + h) * 64) * KVN;
    const unsigned short* peH = peb + (size_t)h * KVN * 64;

    // ---- prologue: Q tile into Pb + K/V tile 0 into buf 0 ----
    #pragma unroll
    for (int c = 0; c < 4; ++c) {
        int row = c*32 + w*8 + jr;
        gl2lds16(qg + ((size_t)(b*1024 + q0 + row))*1024 + h*64 + (l7 ^ sw8(row))*8,
                 &Pb[(c*32 + w*8)*64]);
    }
    {
        #pragma unroll
        for (int c = 0; c < 2; ++c) {
            int row = c*32 + w*8 + jr;
            gl2lds16(kq + kqbase + (size_t)row*1024 + (l7 ^ sw8(row))*8,
                     &Kt[0][(c*32 + w*8)*64]);
            gl2lds16(vh + vhbase + (size_t)row*KVN + (l7 ^ sw8(row))*8,
                     &Vt[0][(c*32 + w*8)*64]);
        }
    }
    __syncthreads();
    short8 qa[2][2];
    #pragma unroll
    for (int it2 = 0; it2 < 2; ++it2) {
        qa[it2][0] = ldfrag(Pb, 32*w + 16*it2 + colq, quad);
        qa[it2][1] = ldfrag(Pb, 32*w + 16*it2 + colq, 4 + quad);
    }

    f32x4 oacc[2][4];
    float l_[2][4];
    #pragma unroll
    for (int it2 = 0; it2 < 2; ++it2) {
        #pragma unroll
        for (int dt = 0; dt < 4; ++dt) oacc[it2][dt] = (f32x4){0.f,0.f,0.f,0.f};
        #pragma unroll
        for (int r = 0; r < 4; ++r) l_[it2][r] = 0.f;
    }
    const f32x4 zero4 = (f32x4){0.f,0.f,0.f,0.f};
    const int nkv = min(36, ((q0 + 1407) >> 6) + 1);

    for (int kvt = 0; kvt < nkv; ++kvt) {
        const int kv0 = kvt * 64;
        const int cur = kvt & 1;
        // ---- prefetch next K/V tile into other buffer (overlaps compute) ----
        if (kvt + 1 < nkv) {
            const int kn0 = kv0 + 64;
            #pragma unroll
            for (int c = 0; c < 2; ++c) {
                int row = c*32 + w*8 + jr;
                gl2lds16(kq + kqbase + (size_t)(kn0 + row)*1024 + (l7 ^ sw8(row))*8,
                         &Kt[cur ^ 1][(c*32 + w*8)*64]);
                gl2lds16(vh + vhbase + (size_t)row*KVN + kn0 + (l7 ^ sw8(row))*8,
                         &Vt[cur ^ 1][(c*32 + w*8)*64]);
            }
        }

        const unsigned short* Kc = Kt[cur];
        const unsigned short* Vc = Vt[cur];
        short8 kf[4][2], vf[4][2];
        #pragma unroll
        for (int nt = 0; nt < 4; ++nt) {
            kf[nt][0] = ldfrag(Kc, nt*16 + colq, quad);
            kf[nt][1] = ldfrag(Kc, nt*16 + colq, 4 + quad);
            vf[nt][0] = ldfrag(Vc, nt*16 + colq, quad);
            vf[nt][1] = ldfrag(Vc, nt*16 + colq, 4 + quad);
        }

        #pragma unroll
        for (int it2 = 0; it2 < 2; ++it2) {
            // PE B-frags from global (issue early; independent of S MFMAs)
            const int cb = kv0 - q0 + 1008 - 32*w - 16*it2;
            short8 pb0[5], pb1[5];
            #pragma unroll
            for (int pnt = 0; pnt < 5; ++pnt) {
                int c = cb + pnt*16 + colq;
                c = max(0, min(c, KVN - 1));   // clamped rows feed masked cols only
                const unsigned short* pr = peH + (size_t)c * 64;
                pb0[pnt] = *(const short8*)(pr + quad*8);
                pb1[pnt] = *(const short8*)(pr + 32 + quad*8);
            }
            // S = Q.K^T (pre-scaled)
            f32x4 facc[4];
            #pragma unroll
            for (int nt = 0; nt < 4; ++nt) {
                f32x4 t = __builtin_amdgcn_mfma_f32_16x16x32_bf16(qa[it2][0], kf[nt][0], zero4, 0, 0, 0);
                facc[nt] = __builtin_amdgcn_mfma_f32_16x16x32_bf16(qa[it2][1], kf[nt][1], t, 0, 0, 0);
            }
            // pos band
            f32x4 pacc[5];
            #pragma unroll
            for (int pnt = 0; pnt < 5; ++pnt) {
                f32x4 t = __builtin_amdgcn_mfma_f32_16x16x32_bf16(qa[it2][0], pb0[pnt], zero4, 0, 0, 0);
                pacc[pnt] = __builtin_amdgcn_mfma_f32_16x16x32_bf16(qa[it2][1], pb1[pnt], t, 0, 0, 0);
            }
            // gather + exp + P write (static-max softmax, l deferred)
            const int prow0 = 32*w + 16*it2 + 4*quad;
            #pragma unroll
            for (int r = 0; r < 4; ++r) {
                int tt = colq + 15 - 4*quad - r;
                int src = (lane & 48) | (tt & 15);
                float sh[5];
                #pragma unroll
                for (int p = 0; p < 5; ++p) sh[p] = __shfl(pacc[p][r], src, 64);
                int ig = q0 + prow0 + r;
                float lsum = 0.f;
                float ps[4];
                #pragma unroll
                for (int nt = 0; nt < 4; ++nt) {
                    float g = (tt < 16) ? sh[nt] : sh[nt + 1];
                    float v = facc[nt][r] + g;
                    int jg = kv0 + nt*16 + colq;
                    float s = (jg - ig > TMEM) ? -1e30f : v;
                    ps[nt] = __expf(s);
                    lsum += ps[nt];
                }
                l_[it2][r] += lsum;
                int prow = prow0 + r;
                int swp = sw8(prow);
                #pragma unroll
                for (int nt = 0; nt < 4; ++nt) {
                    int cc = nt*16 + colq;
                    Pb[prow*64 + (((cc >> 3) ^ swp))*8 + (cc & 7)] = f2bf_us(ps[nt]);
                }
            }
            // PV (same-wave DS ordering: Pb writes visible to own reads)
            short8 pa0 = ldfrag(Pb, 32*w + 16*it2 + colq, quad);
            short8 pa1 = ldfrag(Pb, 32*w + 16*it2 + colq, 4 + quad);
            #pragma unroll
            for (int dt = 0; dt < 4; ++dt) {
                f32x4 t = __builtin_amdgcn_mfma_f32_16x16x32_bf16(pa0, vf[dt][0], oacc[it2][dt], 0, 0, 0);
                oacc[it2][dt] = __builtin_amdgcn_mfma_f32_16x16x32_bf16(pa1, vf[dt][1], t, 0, 0, 0);
            }
        }
        __syncthreads();   // drains prefetch DMA; guards buffer swap
    }

    // ---- epilogue: reduce l across 16 colq lanes, normalize, store ----
    #pragma unroll
    for (int it2 = 0; it2 < 2; ++it2) {
        #pragma unroll
        for (int r = 0; r < 4; ++r) {
            float lt = l_[it2][r];
            #pragma unroll
            for (int off = 1; off < 16; off <<= 1) lt += __shfl_xor(lt, off, 64);
            float inv = 1.0f / lt;
            size_t row = (size_t)(b*1024 + q0 + 32*w + 16*it2 + 4*quad + r);
            #pragma unroll
            for (int dt = 0; dt < 4; ++dt)
                out[row*1024 + h*64 + dt*16 + colq] = __float2bfloat16(oacc[it2][dt][r] * inv);
        }
    }
}

// new_mem = x (fp32 bit copy, 16 MB)
__global__ __launch_bounds__(256) void copy_u4(const uint4* __restrict__ src,
                                               uint4* __restrict__ dst, int n)
{
    int i = blockIdx.x * 256 + threadIdx.x;
    if (i < n) dst[i] = src[i];
}

extern "C" void kernel_launch(void* const* d_in, const int* in_sizes, int n_in,
                              void* d_out, int out_size, void* d_ws, size_t ws_size,
                              hipStream_t stream)
{
    const float* x    = (const float*)d_in[0];
    const float* memp = (const float*)d_in[1];
    const float* cmem = (const float*)d_in[2];
    const float* pe   = (const float*)d_in[3];
    const float* Wq   = (const float*)d_in[5];
    const float* Wkv  = (const float*)d_in[6];
    const float* Wout = (const float*)d_in[7];
    const float* bout = (const float*)d_in[8];
    const float* cw   = (const float*)d_in[9];
    const float* cb   = (const float*)d_in[10];
    float* outp = (float*)d_out;

    // ws layout (bytes), total ~94.9 MB
    char* wsb = (char*)d_ws;
    unsigned short* kvin  = (unsigned short*)(wsb);              // 18,874,368
    unsigned short* knat  = (unsigned short*)(wsb + 18874368);   // 18,874,368
    unsigned short* vhb   = (unsigned short*)(wsb + 37748736);   // 18,874,368
    unsigned short* qb    = (unsigned short*)(wsb + 56623104);   //  8,388,608
    bf16*           ao    = (bf16*)(wsb + 65011712);             //  8,388,608
    unsigned short* wqb   = (unsigned short*)(wsb + 73400320);   //  2,097,152
    unsigned short* wkvb  = (unsigned short*)(wsb + 75497472);   //  4,194,304
    unsigned short* woutb = (unsigned short*)(wsb + 79691776);   //  2,097,152
    unsigned short* cw2b  = (unsigned short*)(wsb + 81788928);   //  8,388,608
    unsigned short* peb   = (unsigned short*)(wsb + 90177536);   //  4,718,592

    pack<<<dim3(9856), 256, 0, stream>>>(x, memp, cmem, Wq, Wkv, Wout, cw, pe,
        kvin, wqb, wkvb, woutb, cw2b, peb);
    // q = x @ (0.125*Wq)^T
    gemm_mfma<1,1><<<dim3(32, 8), 256, 0, stream>>>((const bf16*)kvin, (const bf16*)wqb,
        nullptr, qb, nullptr, 4096, 1024, 1024);
    // kv = kvin @ Wkv^T -> knat (K) + vhb (V transposed per head)
    gemm_mfma<2,0><<<dim3(72, 16), 256, 0, stream>>>((const bf16*)kvin, (const bf16*)wkvb,
        nullptr, knat, vhb, 9216, 2048, 1024);
    // flash attention -> ao
    attn<<<dim3(512), 256, 0, stream>>>(qb, knat, vhb, peb, ao);
    // logits = ao @ Wout^T + bout -> d_out (fp32)
    gemm_mfma<0,0><<<dim3(32, 8), 256, 0, stream>>>(ao, (const bf16*)woutb,
        bout, outp, nullptr, 4096, 1024, 1024);
    // new_mem = x
    copy_u4<<<dim3(4096), 256, 0, stream>>>((const uint4*)x,
        (uint4*)(outp + 4194304), 1048576);
    // new_cmem = conv(mem) as GEMM
    gemm_mfma<0,2><<<dim3(8, 8), 256, 0, stream>>>((const bf16*)kvin, (const bf16*)cw2b,
        cb, outp + 8388608, nullptr, 1024, 1024, 4096);
}

// Round 7
// 568.317 us; speedup vs baseline: 1.3763x; 1.3763x over previous
//
#include <hip/hip_runtime.h>
#include <hip/hip_bf16.h>
#include <hip/hip_fp16.h>
#include <cstdint>
#include <cstddef>
#include <cstring>

using bf16 = __hip_bfloat16;

constexpr int TS    = 1024;
constexpr int DIM   = 1024;
constexpr int MEMN  = 1024;
constexpr int CMEMN = 256;
constexpr int KVN   = 2304;   // CMEM + MEM + T
constexpr int TMEM  = 1280;   // MEM + CMEM

typedef __attribute__((ext_vector_type(8))) short short8;
typedef __attribute__((ext_vector_type(4))) float f32x4;

__device__ __forceinline__ unsigned short f2bf_us(float f){
    __hip_bfloat16 t = __float2bfloat16(f);
    unsigned short us; memcpy(&us, &t, 2); return us;
}
__device__ __forceinline__ int sw8(int row){ return (row & 7) ^ ((row >> 3) & 7); }

// XOR-swizzled LDS tile (rows of 64 shorts, swizzle on 8-short chunks)
__device__ __forceinline__ short8 ldfrag(const unsigned short* base, int row, int chunk) {
    int ch = chunk ^ sw8(row);
    return *(const short8*)(base + row*64 + ch*8);
}
__device__ __forceinline__ void gl2lds16(const void* g, void* l) {
    __builtin_amdgcn_global_load_lds(
        (const __attribute__((address_space(1))) void*)g,
        (__attribute__((address_space(3))) void*)l, 16, 0, 0);
}

// ---------------- pack: fp32 -> bf16 staging ----------------
// Wq is pre-scaled by 0.125 * log2(e) so attention softmax can use exp2
// directly (numerator and denominator consistent).
__global__ __launch_bounds__(256) void pack(
    const float* __restrict__ x, const float* __restrict__ memp,
    const float* __restrict__ cmem, const float* __restrict__ Wq,
    const float* __restrict__ Wkv, const float* __restrict__ Wout,
    const float* __restrict__ cw, const float* __restrict__ pe,
    unsigned short* __restrict__ kvin, unsigned short* __restrict__ wqb,
    unsigned short* __restrict__ wkvb, unsigned short* __restrict__ woutb,
    unsigned short* __restrict__ cw2b, unsigned short* __restrict__ peb)
{
    const size_t t8 = ((size_t)blockIdx.x * 256 + threadIdx.x) * 8;
    unsigned short h[8];
    if (t8 < 9437184) {
        size_t g = t8 >> 10;
        int cc = (int)(t8 & 1023);
        int b = (int)(g / KVN), j = (int)(g % KVN);
        const float* src;
        if (j < CMEMN)      src = cmem + ((size_t)b*CMEMN + j)*1024 + cc;
        else if (j < TMEM)  src = memp + ((size_t)b*MEMN + (j - CMEMN))*1024 + cc;
        else                src = x    + ((size_t)b*TS   + (j - TMEM))*1024 + cc;
        float4 f0 = *(const float4*)src; float4 f1 = *(const float4*)(src + 4);
        h[0]=f2bf_us(f0.x); h[1]=f2bf_us(f0.y); h[2]=f2bf_us(f0.z); h[3]=f2bf_us(f0.w);
        h[4]=f2bf_us(f1.x); h[5]=f2bf_us(f1.y); h[6]=f2bf_us(f1.z); h[7]=f2bf_us(f1.w);
        *(uint4*)(kvin + t8) = *(const uint4*)h;
    } else if (t8 < 13631488) {
        const float* src; unsigned short* dst; float sc = 1.0f;
        if (t8 < 10485760)      { src = Wq   + (t8 - 9437184);  dst = wqb   + (t8 - 9437184);
                                  sc = 0.125f * 1.4426950408889634f; }
        else if (t8 < 12582912) { src = Wkv  + (t8 - 10485760); dst = wkvb  + (t8 - 10485760); }
        else                    { src = Wout + (t8 - 12582912); dst = woutb + (t8 - 12582912); }
        float4 f0 = *(const float4*)src; float4 f1 = *(const float4*)(src + 4);
        h[0]=f2bf_us(f0.x*sc); h[1]=f2bf_us(f0.y*sc); h[2]=f2bf_us(f0.z*sc); h[3]=f2bf_us(f0.w*sc);
        h[4]=f2bf_us(f1.x*sc); h[5]=f2bf_us(f1.y*sc); h[6]=f2bf_us(f1.z*sc); h[7]=f2bf_us(f1.w*sc);
        *(uint4*)dst = *(const uint4*)h;
    } else if (t8 < 17825792) {
        size_t o8 = t8 - 13631488;
        int o = (int)(o8 >> 12); int rem = (int)(o8 & 4095);
        int r = rem >> 10, i = rem & 1023;
        #pragma unroll
        for (int p = 0; p < 8; ++p) h[p] = f2bf_us(cw[(o << 12) + (i + p)*4 + r]);
        *(uint4*)(cw2b + o8) = *(const uint4*)h;
    } else {
        size_t o8 = t8 - 17825792;
        const float* src = pe + o8;
        float4 f0 = *(const float4*)src; float4 f1 = *(const float4*)(src + 4);
        h[0]=f2bf_us(f0.x); h[1]=f2bf_us(f0.y); h[2]=f2bf_us(f0.z); h[3]=f2bf_us(f0.w);
        h[4]=f2bf_us(f1.x); h[5]=f2bf_us(f1.y); h[6]=f2bf_us(f1.z); h[7]=f2bf_us(f1.w);
        *(uint4*)(peb + o8) = *(const uint4*)h;
    }
}

// ---------------- MFMA GEMM (unchanged, R5-proven) ----------------
template<int EPI, int QMODE>
__global__ __launch_bounds__(256) void gemm_mfma(
    const bf16* __restrict__ Abf, const bf16* __restrict__ Bbf,
    const float* __restrict__ bias, void* __restrict__ Cptr,
    void* __restrict__ C2, int M, int N, int K)
{
    __shared__ alignas(16) unsigned short As[128*64];
    __shared__ alignas(16) unsigned short Bs[128*64];
    const int tid = threadIdx.x, lane = tid & 63, w = tid >> 6;
    const int quad = lane >> 4, colq = lane & 15;
    const int wm = w >> 1, wn = w & 1;
    const int m0 = blockIdx.x * 128, n0 = blockIdx.y * 128;
    size_t abase;
    if (QMODE == 0)      abase = (size_t)m0 * K;
    else if (QMODE == 1) abase = ((size_t)((m0 >> 10)*KVN + TMEM + (m0 & 1023))) * 1024;
    else                 abase = ((size_t)((m0 >> 8)*KVN + CMEMN)) * 1024 + (size_t)(m0 & 255) * 4096;
    const unsigned short* Ag = (const unsigned short*)Abf + abase;
    const unsigned short* Bg = (const unsigned short*)Bbf + (size_t)n0 * K;

    const int srow0 = w*32 + (lane >> 3);
    const int sch2  = lane & 7;

    f32x4 acc[4][4];
    #pragma unroll
    for (int i = 0; i < 4; ++i)
        #pragma unroll
        for (int j = 0; j < 4; ++j) acc[i][j] = (f32x4){0.f,0.f,0.f,0.f};

    for (int k0 = 0; k0 < K; k0 += 64) {
        __syncthreads();
        #pragma unroll
        for (int c = 0; c < 4; ++c) {
            int rr = srow0 + c*8;
            int ch = sch2 ^ sw8(rr);
            gl2lds16(Ag + (size_t)rr*K + k0 + ch*8, &As[(w*32 + c*8)*64]);
            gl2lds16(Bg + (size_t)rr*K + k0 + ch*8, &Bs[(w*32 + c*8)*64]);
        }
        __syncthreads();
        short8 af[4][2], bfr[4][2];
        #pragma unroll
        for (int i = 0; i < 4; ++i) {
            af[i][0]  = ldfrag(As, wm*64 + i*16 + colq, quad);
            af[i][1]  = ldfrag(As, wm*64 + i*16 + colq, 4 + quad);
            bfr[i][0] = ldfrag(Bs, wn*64 + i*16 + colq, quad);
            bfr[i][1] = ldfrag(Bs, wn*64 + i*16 + colq, 4 + quad);
        }
        #pragma unroll
        for (int i = 0; i < 4; ++i)
            #pragma unroll
            for (int j = 0; j < 4; ++j) {
                f32x4 t = __builtin_amdgcn_mfma_f32_16x16x32_bf16(af[i][0], bfr[j][0], acc[i][j], 0, 0, 0);
                acc[i][j] = __builtin_amdgcn_mfma_f32_16x16x32_bf16(af[i][1], bfr[j][1], t, 0, 0, 0);
            }
    }
    if (EPI == 2) {
        const int b = m0 / KVN;
        const int jj0 = (m0 - b*KVN) + wm*64;
        if (n0 < 1024) {
            bf16* kn = (bf16*)Cptr;
            #pragma unroll
            for (int j = 0; j < 4; ++j) {
                int col = n0 + wn*64 + j*16 + colq;
                #pragma unroll
                for (int i = 0; i < 4; ++i)
                    #pragma unroll
                    for (int r = 0; r < 4; ++r)
                        kn[(size_t)(b*KVN + jj0 + i*16 + quad*4 + r)*1024 + col] =
                            __float2bfloat16(acc[i][j][r]);
            }
        } else {
            unsigned short* vp = (unsigned short*)C2;
            #pragma unroll
            for (int j = 0; j < 4; ++j) {
                int col = n0 + wn*64 + j*16 + colq;
                int hh = (col >> 6) & 15, d = col & 63;
                #pragma unroll
                for (int i = 0; i < 4; ++i) {
                    int jjb = jj0 + i*16 + quad*4;
                    ushort4 u;
                    u.x = f2bf_us(acc[i][j][0]); u.y = f2bf_us(acc[i][j][1]);
                    u.z = f2bf_us(acc[i][j][2]); u.w = f2bf_us(acc[i][j][3]);
                    *(ushort4*)(vp + ((size_t)((b*16 + hh)*64 + d))*KVN + jjb) = u;
                }
            }
        }
    } else {
        #pragma unroll
        for (int j = 0; j < 4; ++j) {
            int col = n0 + wn*64 + j*16 + colq;
            float bj = bias ? bias[col] : 0.0f;
            #pragma unroll
            for (int i = 0; i < 4; ++i)
                #pragma unroll
                for (int r = 0; r < 4; ++r) {
                    size_t row = (size_t)(m0 + wm*64 + i*16 + quad*4 + r);
                    float v = acc[i][j][r] + bj;
                    if (EPI == 1) ((bf16*)Cptr)[row*N + col] = __float2bfloat16(v);
                    else          ((float*)Cptr)[row*N + col] = v;
                }
        }
    }
}

// ---------------- Flash attention, rel-pos, MFMA ----------------
// R7 = R5 (PE in LDS ring) + pipelined staging: at the TOP of tile t, DMA
// K/V(t+1) into the spare buffer and the next 64 PE ring rows; single barrier
// at tile end drains after a full tile of compute (latency hidden).
// Ring slot disjointness: tile t reads ring rows [kv0-q0+896, +1087] (192),
// prefetch writes [kv0-q0+1088, +1151] ≡ mod 256 the rows tile t-1 read.
// Softmax: q pre-scaled by 0.125*log2e -> raw exp2f; interior tiles skip the
// causal-mask selects (wave-uniform branch).
__global__ __launch_bounds__(256) void attn(
    const unsigned short* __restrict__ qg,   // prescaled q bf16 [b*1024+i][1024]
    const unsigned short* __restrict__ kq,   // knat [b*KVN+j][1024]
    const unsigned short* __restrict__ vh,   // Vh [((b*16+h)*64+d)][KVN]
    const unsigned short* __restrict__ peb,  // [h][KVN][64] bf16
    bf16* __restrict__ out)                  // ao [b*1024+i][1024]
{
    __shared__ alignas(16) unsigned short Kt[2][64*64];   // 16 KB
    __shared__ alignas(16) unsigned short Vt[2][64*64];   // 16 KB, Vt[d][j]
    __shared__ alignas(16) unsigned short PEr[256*64];    // 32 KB ring
    __shared__ alignas(16) unsigned short Pb[128*64];     // 16 KB, Q then P

    const int tid  = threadIdx.x;
    const int lane = tid & 63, w = tid >> 6;
    const int quad = lane >> 4, colq = lane & 15;
    const int jr = lane >> 3, l7 = lane & 7;

    const int bx = blockIdx.x;
    const int b = bx & 3, h = (bx >> 2) & 15;
    const int q0 = (7 - (bx >> 6)) * 128;      // heavy q-tiles dispatch first

    const size_t kqbase = (size_t)b * KVN * 1024 + h*64;
    const size_t vhbase = ((size_t)(b*16 + h) * 64) * KVN;
    const unsigned short* peH = peb + (size_t)h * KVN * 64;

    // ---- prologue: Q tile, K/V tile 0 (buf 0), PE ring rows [896-q0, +191] --
    #pragma unroll
    for (int c = 0; c < 4; ++c) {
        int row = c*32 + w*8 + jr;
        gl2lds16(qg + ((size_t)(b*1024 + q0 + row))*1024 + h*64 + (l7 ^ sw8(row))*8,
                 &Pb[(c*32 + w*8)*64]);
    }
    #pragma unroll
    for (int c = 0; c < 2; ++c) {
        int row = c*32 + w*8 + jr;
        gl2lds16(kq + kqbase + (size_t)row*1024 + (l7 ^ sw8(row))*8,
                 &Kt[0][(c*32 + w*8)*64]);
        gl2lds16(vh + vhbase + (size_t)row*KVN + (l7 ^ sw8(row))*8,
                 &Vt[0][(c*32 + w*8)*64]);
    }
    const int c0p = 896 - q0;                 // >= 0 (q0 <= 896), max 1087
    #pragma unroll
    for (int c = 0; c < 6; ++c) {
        int cg = c0p + c*32 + w*8 + jr;       // in [0, 1087]: no clamp needed
        gl2lds16(peH + (size_t)cg*64 + (l7 ^ sw8(cg))*8,
                 &PEr[((c0p + c*32 + w*8) & 255)*64]);
    }
    __syncthreads();
    short8 qa[2][2];
    #pragma unroll
    for (int it2 = 0; it2 < 2; ++it2) {
        qa[it2][0] = ldfrag(Pb, 32*w + 16*it2 + colq, quad);
        qa[it2][1] = ldfrag(Pb, 32*w + 16*it2 + colq, 4 + quad);
    }

    f32x4 oacc[2][4];
    float l_[2][4];
    #pragma unroll
    for (int it2 = 0; it2 < 2; ++it2) {
        #pragma unroll
        for (int dt = 0; dt < 4; ++dt) oacc[it2][dt] = (f32x4){0.f,0.f,0.f,0.f};
        #pragma unroll
        for (int r = 0; r < 4; ++r) l_[it2][r] = 0.f;
    }
    const f32x4 zero4 = (f32x4){0.f,0.f,0.f,0.f};
    const int nkv = min(36, ((q0 + 1407) >> 6) + 1);

    for (int kvt = 0; kvt < nkv; ++kvt) {
        const int kv0 = kvt * 64;
        const int cur = kvt & 1;

        // ---- prefetch tile t+1 (K/V -> spare buf, PE -> ring) ----
        if (kvt + 1 < nkv) {
            const int kn0 = kv0 + 64;
            #pragma unroll
            for (int c = 0; c < 2; ++c) {
                int row = c*32 + w*8 + jr;
                gl2lds16(kq + kqbase + (size_t)(kn0 + row)*1024 + (l7 ^ sw8(row))*8,
                         &Kt[cur ^ 1][(c*32 + w*8)*64]);
                gl2lds16(vh + vhbase + (size_t)row*KVN + kn0 + (l7 ^ sw8(row))*8,
                         &Vt[cur ^ 1][(c*32 + w*8)*64]);
            }
            const int cbase = kv0 - q0 + 1088;     // new rows for t+1
            #pragma unroll
            for (int c = 0; c < 2; ++c) {
                int cg = cbase + c*32 + w*8 + jr;  // >= 192 >= 0
                int cs = min(cg, KVN - 1);         // clamped rows feed masked cols
                gl2lds16(peH + (size_t)cs*64 + (l7 ^ sw8(cg & 255))*8,
                         &PEr[((cbase + c*32 + w*8) & 255)*64]);
            }
        }

        const unsigned short* Kc = Kt[cur];
        const unsigned short* Vc = Vt[cur];
        short8 kf[4][2], vf[4][2];
        #pragma unroll
        for (int nt = 0; nt < 4; ++nt) {
            kf[nt][0] = ldfrag(Kc, nt*16 + colq, quad);
            kf[nt][1] = ldfrag(Kc, nt*16 + colq, 4 + quad);
            vf[nt][0] = ldfrag(Vc, nt*16 + colq, quad);
            vf[nt][1] = ldfrag(Vc, nt*16 + colq, 4 + quad);
        }

        #pragma unroll
        for (int it2 = 0; it2 < 2; ++it2) {
            // S = Q.K^T (pre-scaled by 0.125*log2e)
            f32x4 facc[4];
            #pragma unroll
            for (int nt = 0; nt < 4; ++nt) {
                f32x4 t = __builtin_amdgcn_mfma_f32_16x16x32_bf16(qa[it2][0], kf[nt][0], zero4, 0, 0, 0);
                facc[nt] = __builtin_amdgcn_mfma_f32_16x16x32_bf16(qa[it2][1], kf[nt][1], t, 0, 0, 0);
            }
            // pos band from ring
            const int cb = kv0 - q0 + 1008 - 32*w - 16*it2;
            f32x4 pacc[5];
            #pragma unroll
            for (int pnt = 0; pnt < 5; ++pnt) {
                int slot = (cb + pnt*16 + colq) & 255;
                short8 b0 = ldfrag(PEr, slot, quad);
                short8 b1 = ldfrag(PEr, slot, 4 + quad);
                f32x4 t = __builtin_amdgcn_mfma_f32_16x16x32_bf16(qa[it2][0], b0, zero4, 0, 0, 0);
                pacc[pnt] = __builtin_amdgcn_mfma_f32_16x16x32_bf16(qa[it2][1], b1, t, 0, 0, 0);
            }
            // gather + exp2 + P write (static-max softmax, l deferred)
            const int prow0 = 32*w + 16*it2 + 4*quad;
            const bool anymask = (kv0 + 63) - (q0 + 32*w + 16*it2) > TMEM;
            #pragma unroll
            for (int r = 0; r < 4; ++r) {
                int tt = colq + 15 - 4*quad - r;
                int src = (lane & 48) | (tt & 15);
                float sh[5];
                #pragma unroll
                for (int p = 0; p < 5; ++p) sh[p] = __shfl(pacc[p][r], src, 64);
                float lsum = 0.f;
                float ps[4];
                if (anymask) {
                    int ig = q0 + prow0 + r;
                    #pragma unroll
                    for (int nt = 0; nt < 4; ++nt) {
                        float g = (tt < 16) ? sh[nt] : sh[nt + 1];
                        float v = facc[nt][r] + g;
                        int jg = kv0 + nt*16 + colq;
                        float s = (jg - ig > TMEM) ? -1e30f : v;
                        ps[nt] = exp2f(s);
                        lsum += ps[nt];
                    }
                } else {
                    #pragma unroll
                    for (int nt = 0; nt < 4; ++nt) {
                        float g = (tt < 16) ? sh[nt] : sh[nt + 1];
                        ps[nt] = exp2f(facc[nt][r] + g);
                        lsum += ps[nt];
                    }
                }
                l_[it2][r] += lsum;
                int prow = prow0 + r;
                int swp = sw8(prow);
                #pragma unroll
                for (int nt = 0; nt < 4; ++nt) {
                    int cc = nt*16 + colq;
                    Pb[prow*64 + (((cc >> 3) ^ swp))*8 + (cc & 7)] = f2bf_us(ps[nt]);
                }
            }
            // PV (same-wave DS ordering: Pb writes visible to own reads)
            short8 pa0 = ldfrag(Pb, 32*w + 16*it2 + colq, quad);
            short8 pa1 = ldfrag(Pb, 32*w + 16*it2 + colq, 4 + quad);
            #pragma unroll
            for (int dt = 0; dt < 4; ++dt) {
                f32x4 t = __builtin_amdgcn_mfma_f32_16x16x32_bf16(pa0, vf[dt][0], oacc[it2][dt], 0, 0, 0);
                oacc[it2][dt] = __builtin_amdgcn_mfma_f32_16x16x32_bf16(pa1, vf[dt][1], t, 0, 0, 0);
            }
        }
        __syncthreads();   // drains prefetch DMA (issued a full tile ago)
    }

    // ---- epilogue: reduce l across 16 colq lanes, normalize, store ----
    #pragma unroll
    for (int it2 = 0; it2 < 2; ++it2) {
        #pragma unroll
        for (int r = 0; r < 4; ++r) {
            float lt = l_[it2][r];
            #pragma unroll
            for (int off = 1; off < 16; off <<= 1) lt += __shfl_xor(lt, off, 64);
            float inv = 1.0f / lt;
            size_t row = (size_t)(b*1024 + q0 + 32*w + 16*it2 + 4*quad + r);
            #pragma unroll
            for (int dt = 0; dt < 4; ++dt)
                out[row*1024 + h*64 + dt*16 + colq] = __float2bfloat16(oacc[it2][dt][r] * inv);
        }
    }
}

// new_mem = x (fp32 bit copy, 16 MB)
__global__ __launch_bounds__(256) void copy_u4(const uint4* __restrict__ src,
                                               uint4* __restrict__ dst, int n)
{
    int i = blockIdx.x * 256 + threadIdx.x;
    if (i < n) dst[i] = src[i];
}

extern "C" void kernel_launch(void* const* d_in, const int* in_sizes, int n_in,
                              void* d_out, int out_size, void* d_ws, size_t ws_size,
                              hipStream_t stream)
{
    const float* x    = (const float*)d_in[0];
    const float* memp = (const float*)d_in[1];
    const float* cmem = (const float*)d_in[2];
    const float* pe   = (const float*)d_in[3];
    const float* Wq   = (const float*)d_in[5];
    const float* Wkv  = (const float*)d_in[6];
    const float* Wout = (const float*)d_in[7];
    const float* bout = (const float*)d_in[8];
    const float* cw   = (const float*)d_in[9];
    const float* cb   = (const float*)d_in[10];
    float* outp = (float*)d_out;

    // ws layout (bytes), total ~94.9 MB
    char* wsb = (char*)d_ws;
    unsigned short* kvin  = (unsigned short*)(wsb);              // 18,874,368
    unsigned short* knat  = (unsigned short*)(wsb + 18874368);   // 18,874,368
    unsigned short* vhb   = (unsigned short*)(wsb + 37748736);   // 18,874,368
    unsigned short* qb    = (unsigned short*)(wsb + 56623104);   //  8,388,608
    bf16*           ao    = (bf16*)(wsb + 65011712);             //  8,388,608
    unsigned short* wqb   = (unsigned short*)(wsb + 73400320);   //  2,097,152
    unsigned short* wkvb  = (unsigned short*)(wsb + 75497472);   //  4,194,304
    unsigned short* woutb = (unsigned short*)(wsb + 79691776);   //  2,097,152
    unsigned short* cw2b  = (unsigned short*)(wsb + 81788928);   //  8,388,608
    unsigned short* peb   = (unsigned short*)(wsb + 90177536);   //  4,718,592

    pack<<<dim3(9856), 256, 0, stream>>>(x, memp, cmem, Wq, Wkv, Wout, cw, pe,
        kvin, wqb, wkvb, woutb, cw2b, peb);
    // q = x @ (0.125*log2e*Wq)^T
    gemm_mfma<1,1><<<dim3(32, 8), 256, 0, stream>>>((const bf16*)kvin, (const bf16*)wqb,
        nullptr, qb, nullptr, 4096, 1024, 1024);
    // kv = kvin @ Wkv^T -> knat (K) + vhb (V transposed per head)
    gemm_mfma<2,0><<<dim3(72, 16), 256, 0, stream>>>((const bf16*)kvin, (const bf16*)wkvb,
        nullptr, knat, vhb, 9216, 2048, 1024);
    // flash attention -> ao
    attn<<<dim3(512), 256, 0, stream>>>(qb, knat, vhb, peb, ao);
    // logits = ao @ Wout^T + bout -> d_out (fp32)
    gemm_mfma<0,0><<<dim3(32, 8), 256, 0, stream>>>(ao, (const bf16*)woutb,
        bout, outp, nullptr, 4096, 1024, 1024);
    // new_mem = x
    copy_u4<<<dim3(4096), 256, 0, stream>>>((const uint4*)x,
        (uint4*)(outp + 4194304), 1048576);
    // new_cmem = conv(mem) as GEMM
    gemm_mfma<0,2><<<dim3(8, 8), 256, 0, stream>>>((const bf16*)kvin, (const bf16*)cw2b,
        cb, outp + 8388608, nullptr, 1024, 1024, 4096);
}